// Round 1
// baseline (226.204 us; speedup 1.0000x reference)
//
#include <hip/hip_runtime.h>

// out = sign * FWHT(x), x: 16384 x 2048 fp32, normalized by 2^-5.5,
// sign = -1 for n >= 3N/4 (n >= 1536).
//
// One 256-thread block per row. Row (8 KiB) staged in LDS with +1-per-8
// padding (addr(n) = n + (n>>3)) so all gather patterns are <=3-way
// (mostly 2-way = free) on the 32-bank LDS.
// 11 stages = 3 register stages (bits 0-2) + 3 (bits 3-5) + 3 (bits 6-8)
// + 2 (bits 9-10); stages on distinct bits commute with the reference's
// ascending-h order, so any grouping is exact.

#define NN 2048
#define PADDR(n) ((n) + ((n) >> 3))

__device__ __forceinline__ void fwht8(float v[8]) {
    // stride 1 (bit 0)
#pragma unroll
    for (int i = 0; i < 8; i += 2) {
        float a = v[i], b = v[i + 1];
        v[i] = a + b; v[i + 1] = a - b;
    }
    // stride 2 (bit 1)
#pragma unroll
    for (int i = 0; i < 8; i += 4) {
        float a0 = v[i], a1 = v[i + 1], b0 = v[i + 2], b1 = v[i + 3];
        v[i] = a0 + b0; v[i + 1] = a1 + b1;
        v[i + 2] = a0 - b0; v[i + 3] = a1 - b1;
    }
    // stride 4 (bit 2)
#pragma unroll
    for (int i = 0; i < 4; ++i) {
        float a = v[i], b = v[i + 4];
        v[i] = a + b; v[i + 4] = a - b;
    }
}

__global__ __launch_bounds__(256) void fwht_sign_kernel(const float* __restrict__ x,
                                                        float* __restrict__ out) {
    __shared__ float s[NN + NN / 8];  // 2304 floats = 9216 B
    const int t = threadIdx.x;
    const long long row = blockIdx.x;
    const float* __restrict__ xr = x + row * (long long)NN;
    float* __restrict__ outr = out + row * (long long)NN;

    float v[8];

    // ---- Phase 1: load 8 contiguous, FWHT bits 0-2, scatter to LDS ----
    {
        const float4 lo = *reinterpret_cast<const float4*>(xr + 8 * t);
        const float4 hi = *reinterpret_cast<const float4*>(xr + 8 * t + 4);
        v[0] = lo.x; v[1] = lo.y; v[2] = lo.z; v[3] = lo.w;
        v[4] = hi.x; v[5] = hi.y; v[6] = hi.z; v[7] = hi.w;
        fwht8(v);
        const int base = PADDR(8 * t);  // = 9*t, 8 contiguous padded slots
#pragma unroll
        for (int r = 0; r < 8; ++r) s[base + r] = v[r];
    }
    __syncthreads();

    // ---- Phase 2: bits 3-5 (stride 8). Each location touched by exactly
    // one thread, so no sync between read and write-back. ----
    {
        const int u = t & 7, w = t >> 3;
        const int n0 = w * 64 + u;
        const int base = n0 + (n0 >> 3);  // + 9*r per step
#pragma unroll
        for (int r = 0; r < 8; ++r) v[r] = s[base + 9 * r];
        fwht8(v);
#pragma unroll
        for (int r = 0; r < 8; ++r) s[base + 9 * r] = v[r];
    }
    __syncthreads();

    // ---- Phase 3: bits 6-8 (stride 64) ----
    {
        const int u = t & 63, w = t >> 6;
        const int n0 = w * 512 + u;
        const int base = n0 + (n0 >> 3);  // + 72*r per step
#pragma unroll
        for (int r = 0; r < 8; ++r) v[r] = s[base + 72 * r];
        fwht8(v);
#pragma unroll
        for (int r = 0; r < 8; ++r) s[base + 72 * r] = v[r];
    }
    __syncthreads();

    // ---- Phase 4: bits 9-10 (strides 512,1024), fuse scale+sign, store ----
    const float M = 0.022097086912079608f;  // 2^-5.5
#pragma unroll
    for (int g = 0; g < 2; ++g) {
        const int j = t + 256 * g;
        const int b = j + (j >> 3);
        const float c0 = s[b];                        // n = j
        const float c1 = s[b + PADDR(512)  - 0];      // n = j + 512  -> +576
        const float c2 = s[b + 1152];                 // n = j + 1024 -> +1152
        const float c3 = s[b + 1728];                 // n = j + 1536 -> +1728
        const float d0 = c0 + c1, d1 = c0 - c1;
        const float d2 = c2 + c3, d3 = c2 - c3;
        outr[j]          = (d0 + d2) * M;
        outr[j + 512]    = (d1 + d3) * M;
        outr[j + 1024]   = (d0 - d2) * M;
        outr[j + 1536]   = (d1 - d3) * (-M);  // sign flip: n >= 1536
    }
}

extern "C" void kernel_launch(void* const* d_in, const int* in_sizes, int n_in,
                              void* d_out, int out_size, void* d_ws, size_t ws_size,
                              hipStream_t stream) {
    const float* x = (const float*)d_in[0];
    float* out = (float*)d_out;
    const int rows = in_sizes[0] / NN;  // 16384
    fwht_sign_kernel<<<dim3(rows), dim3(256), 0, stream>>>(x, out);
}